// Round 1
// baseline (3345.270 us; speedup 1.0000x reference)
//
#include <hip/hip_runtime.h>
#include <math.h>

#define B_  32
#define S_  512
#define H_  16
#define DH_ 64
#define DM_ 1024
#define T_  512

// sizes
#define NBHSD (B_*H_*S_*DH_)          // 16,777,216 elements (also B*S*DM)
#define OFF_ATTN ((size_t)B_*S_*DM_)  // mha_out element count in d_out

// ---------------------------------------------------------------------------
// Kernel 1: per-head Q/K/V projection.
//   out[b,h,s,e] = sum_d x[b,s,d] * W[h,e,d] + bias[h,e]
// grid (S/64, H, 3*B), block 256. 64s x 64e tile, K=64 in 2 chunks of 32.
// ---------------------------------------------------------------------------
__global__ __launch_bounds__(256)
void qkv_proj_kernel(const float* __restrict__ q_in, const float* __restrict__ k_in,
                     const float* __restrict__ v_in,
                     const float* __restrict__ Wq, const float* __restrict__ bq,
                     const float* __restrict__ Wk, const float* __restrict__ bk,
                     const float* __restrict__ Wv, const float* __restrict__ bv,
                     float* __restrict__ Qo, float* __restrict__ Ko, float* __restrict__ Vo)
{
    const int stile = blockIdx.x;        // 8 tiles of 64 s-rows
    const int h     = blockIdx.y;
    const int which = blockIdx.z / B_;   // 0=q,1=k,2=v
    const int b     = blockIdx.z % B_;

    const float* xin; const float* W; const float* bias; float* out;
    if (which == 0)      { xin = q_in; W = Wq; bias = bq; out = Qo; }
    else if (which == 1) { xin = k_in; W = Wk; bias = bk; out = Ko; }
    else                 { xin = v_in; W = Wv; bias = bv; out = Vo; }

    __shared__ float sA[32*68];   // [d][s]  X^T chunk
    __shared__ float sW[32*68];   // [d][e]  W^T chunk

    const int tid = threadIdx.x;
    const int dg = tid & 15;      // e quad: e = dg*4 + j
    const int tg = tid >> 4;      // s quad: s = tg*4 + i  (within tile)
    const int s0 = stile * 64;

    float acc[4][4];
    #pragma unroll
    for (int i=0;i<4;i++)
        #pragma unroll
        for (int j=0;j<4;j++) acc[i][j]=0.f;

    for (int dc = 0; dc < 64; dc += 32) {
        __syncthreads();
        // load X rows [64 s][32 d] -> sA[d][s]
        for (int idx = tid; idx < 64*32; idx += 256) {
            int s = idx >> 5, d = idx & 31;
            sA[d*68 + s] = xin[((size_t)b*S_ + s0 + s)*DH_ + dc + d];
        }
        // load W [64 e][32 d] -> sW[d][e]
        for (int idx = tid; idx < 64*32; idx += 256) {
            int e = idx >> 5, d = idx & 31;
            sW[d*68 + e] = W[(size_t)h*DH_*DH_ + (size_t)e*DH_ + dc + d];
        }
        __syncthreads();
        #pragma unroll
        for (int kk = 0; kk < 32; kk++) {
            const float4 a4 = *(const float4*)&sA[kk*68 + tg*4];
            const float4 w4 = *(const float4*)&sW[kk*68 + dg*4];
            const float a[4] = {a4.x,a4.y,a4.z,a4.w};
            const float w[4] = {w4.x,w4.y,w4.z,w4.w};
            #pragma unroll
            for (int i=0;i<4;i++)
                #pragma unroll
                for (int j=0;j<4;j++)
                    acc[i][j] = fmaf(a[i], w[j], acc[i][j]);
        }
    }

    // store with bias along e (columns)
    const float4 bv4 = *(const float4*)&bias[h*DH_ + dg*4];
    const float bb[4] = {bv4.x,bv4.y,bv4.z,bv4.w};
    #pragma unroll
    for (int i=0;i<4;i++) {
        int s = s0 + tg*4 + i;
        float4 o;
        o.x = acc[i][0]+bb[0]; o.y = acc[i][1]+bb[1];
        o.z = acc[i][2]+bb[2]; o.w = acc[i][3]+bb[3];
        *(float4*)&out[(((size_t)b*H_ + h)*S_ + s)*DH_ + dg*4] = o;
    }
}

// ---------------------------------------------------------------------------
// Kernel 2/4 (shared): Y[bh][m][d] = sum_k A[m][k] * X[bh][k][d]  (+bias[m])
//   A is [M][K] dense (per-bh offset a_bh_stride); X is [bh][K][64].
//   Output addressing: Y[(bh>>4)*y_b_stride + (bh&15)*y_h_stride
//                        + (mtile*64+m)*y_row_stride + d]
// grid (M/64, B*H), block 256.
// ---------------------------------------------------------------------------
__global__ __launch_bounds__(256)
void gemm_tile64_kernel(const float* __restrict__ A, long a_bh_stride, int K,
                        const float* __restrict__ X, long x_bh_stride,
                        const float* __restrict__ bias,
                        float* __restrict__ Y, long y_b_stride, long y_h_stride,
                        int y_row_stride)
{
    const int mtile = blockIdx.x;
    const int bh    = blockIdx.y;

    const float* Ab = A + (long)bh * a_bh_stride + (long)mtile*64*K;
    const float* Xb = X + (long)bh * x_bh_stride;

    __shared__ float sA[32*68];   // [k][m]
    __shared__ float sX[32*68];   // [k][d]

    const int tid = threadIdx.x;
    const int dg = tid & 15;      // d = dg*4 + j
    const int tg = tid >> 4;      // m = tg*4 + i

    float acc[4][4];
    #pragma unroll
    for (int i=0;i<4;i++)
        #pragma unroll
        for (int j=0;j<4;j++) acc[i][j]=0.f;

    for (int kc = 0; kc < K; kc += 32) {
        __syncthreads();
        // A tile [64 m][32 k] -> sA[k][m] (transposed)
        for (int idx = tid; idx < 64*32; idx += 256) {
            int m = idx >> 5, k = idx & 31;
            sA[k*68 + m] = Ab[(long)m*K + kc + k];
        }
        // X tile [32 k][64 d] -> sX[k][d]
        for (int idx = tid; idx < 32*64; idx += 256) {
            int k = idx >> 6, d = idx & 63;
            sX[k*68 + d] = Xb[(long)(kc + k)*64 + d];
        }
        __syncthreads();
        #pragma unroll
        for (int kk = 0; kk < 32; kk++) {
            const float4 a4 = *(const float4*)&sA[kk*68 + tg*4];
            const float4 x4 = *(const float4*)&sX[kk*68 + dg*4];
            const float a[4] = {a4.x,a4.y,a4.z,a4.w};
            const float x[4] = {x4.x,x4.y,x4.z,x4.w};
            #pragma unroll
            for (int i=0;i<4;i++)
                #pragma unroll
                for (int j=0;j<4;j++)
                    acc[i][j] = fmaf(a[i], x[j], acc[i][j]);
        }
    }

    const long ybase = (long)(bh >> 4)*y_b_stride + (long)(bh & 15)*y_h_stride
                     + (long)mtile*64*y_row_stride;
    #pragma unroll
    for (int i=0;i<4;i++) {
        int m = tg*4 + i;
        float bval = bias ? bias[mtile*64 + m] : 0.f;
        float4 o;
        o.x = acc[i][0]+bval; o.y = acc[i][1]+bval;
        o.z = acc[i][2]+bval; o.w = acc[i][3]+bval;
        *(float4*)&Y[ybase + (long)m*y_row_stride + dg*4] = o;
    }
}

// ---------------------------------------------------------------------------
// Kernel 3: scores + softmax.
//   scores[s,t] = 0.125 * sum_d Q[bh,s,d]*KEt[bh,t,d]; attn = softmax_t
// grid (S/16, B*H), block 256. 16 s-rows per block; t looped in chunks of 64.
// ---------------------------------------------------------------------------
__global__ __launch_bounds__(256)
void attn_softmax_kernel(const float* __restrict__ Q, const float* __restrict__ KEt,
                         float* __restrict__ attnOut)
{
    const int stile = blockIdx.x;   // 32 tiles of 16 rows
    const int bh    = blockIdx.y;

    __shared__ float sQ[16*68];
    __shared__ float sK[64*68];
    __shared__ float sS[16*520];

    const int tid = threadIdx.x;
    const int s0 = stile * 16;

    for (int idx = tid; idx < 16*64; idx += 256) {
        int r = idx >> 6, d = idx & 63;
        sQ[r*68 + d] = Q[((size_t)bh*S_ + s0 + r)*DH_ + d];
    }

    const int sg = tid & 7;    // s = sg*2 + ii
    const int tg = tid >> 3;   // t (within chunk) = tg*2 + j

    for (int tc = 0; tc < 8; tc++) {
        __syncthreads();
        for (int idx = tid; idx < 64*64; idx += 256) {
            int t = idx >> 6, d = idx & 63;
            sK[t*68 + d] = KEt[((size_t)bh*T_ + tc*64 + t)*DH_ + d];
        }
        __syncthreads();
        float acc[2][2] = {{0.f,0.f},{0.f,0.f}};
        #pragma unroll
        for (int d = 0; d < 64; d += 4) {
            const float4 q0 = *(const float4*)&sQ[(sg*2+0)*68 + d];
            const float4 q1 = *(const float4*)&sQ[(sg*2+1)*68 + d];
            const float4 k0 = *(const float4*)&sK[(tg*2+0)*68 + d];
            const float4 k1 = *(const float4*)&sK[(tg*2+1)*68 + d];
            acc[0][0] = fmaf(q0.x,k0.x,fmaf(q0.y,k0.y,fmaf(q0.z,k0.z,fmaf(q0.w,k0.w,acc[0][0]))));
            acc[0][1] = fmaf(q0.x,k1.x,fmaf(q0.y,k1.y,fmaf(q0.z,k1.z,fmaf(q0.w,k1.w,acc[0][1]))));
            acc[1][0] = fmaf(q1.x,k0.x,fmaf(q1.y,k0.y,fmaf(q1.z,k0.z,fmaf(q1.w,k0.w,acc[1][0]))));
            acc[1][1] = fmaf(q1.x,k1.x,fmaf(q1.y,k1.y,fmaf(q1.z,k1.z,fmaf(q1.w,k1.w,acc[1][1]))));
        }
        sS[(sg*2+0)*520 + tc*64 + tg*2+0] = acc[0][0]*0.125f;
        sS[(sg*2+0)*520 + tc*64 + tg*2+1] = acc[0][1]*0.125f;
        sS[(sg*2+1)*520 + tc*64 + tg*2+0] = acc[1][0]*0.125f;
        sS[(sg*2+1)*520 + tc*64 + tg*2+1] = acc[1][1]*0.125f;
    }
    __syncthreads();

    // softmax: 4 waves x 4 rows
    const int wave = tid >> 6, lane = tid & 63;
    for (int rr = 0; rr < 4; rr++) {
        const int r = wave*4 + rr;
        float v[8];
        float m = -INFINITY;
        #pragma unroll
        for (int i = 0; i < 8; i++) {
            v[i] = sS[r*520 + i*64 + lane];
            m = fmaxf(m, v[i]);
        }
        #pragma unroll
        for (int off = 32; off >= 1; off >>= 1) m = fmaxf(m, __shfl_xor(m, off));
        float sum = 0.f;
        #pragma unroll
        for (int i = 0; i < 8; i++) { v[i] = __expf(v[i] - m); sum += v[i]; }
        #pragma unroll
        for (int off = 32; off >= 1; off >>= 1) sum += __shfl_xor(sum, off);
        const float inv = 1.f / sum;
        #pragma unroll
        for (int i = 0; i < 8; i++)
            attnOut[((size_t)bh*S_ + s0 + r)*T_ + i*64 + lane] = v[i]*inv;
    }
}

// ---------------------------------------------------------------------------
// Kernel 5: out projection. C[i][m] = sum_k MHA[i][k]*Wout[m][k] + bout[m]
// grid (B*S/64, DM/64), block 256.
// ---------------------------------------------------------------------------
__global__ __launch_bounds__(256)
void outproj_kernel(const float* __restrict__ MHA, const float* __restrict__ Wout,
                    const float* __restrict__ bout, float* __restrict__ Yout)
{
    const int itile = blockIdx.x;  // rows of i
    const int mtile = blockIdx.y;  // cols of m
    const int i0 = itile*64, m0 = mtile*64;

    __shared__ float sA[32*68];   // [k][i]
    __shared__ float sW[32*68];   // [k][m]

    const int tid = threadIdx.x;
    const int dg = tid & 15;      // m = m0 + dg*4 + j
    const int tg = tid >> 4;      // i = i0 + tg*4 + ii

    float acc[4][4];
    #pragma unroll
    for (int i=0;i<4;i++)
        #pragma unroll
        for (int j=0;j<4;j++) acc[i][j]=0.f;

    for (int kc = 0; kc < DM_; kc += 32) {
        __syncthreads();
        for (int idx = tid; idx < 64*32; idx += 256) {
            int r = idx >> 5, k = idx & 31;
            sA[k*68 + r] = MHA[(long)(i0 + r)*DM_ + kc + k];
        }
        for (int idx = tid; idx < 64*32; idx += 256) {
            int r = idx >> 5, k = idx & 31;
            sW[k*68 + r] = Wout[(long)(m0 + r)*DM_ + kc + k];
        }
        __syncthreads();
        #pragma unroll
        for (int kk = 0; kk < 32; kk++) {
            const float4 a4 = *(const float4*)&sA[kk*68 + tg*4];
            const float4 w4 = *(const float4*)&sW[kk*68 + dg*4];
            const float a[4] = {a4.x,a4.y,a4.z,a4.w};
            const float w[4] = {w4.x,w4.y,w4.z,w4.w};
            #pragma unroll
            for (int i=0;i<4;i++)
                #pragma unroll
                for (int j=0;j<4;j++)
                    acc[i][j] = fmaf(a[i], w[j], acc[i][j]);
        }
    }

    const float4 b4 = *(const float4*)&bout[m0 + dg*4];
    const float bb[4] = {b4.x,b4.y,b4.z,b4.w};
    #pragma unroll
    for (int i=0;i<4;i++) {
        float4 o;
        o.x = acc[i][0]+bb[0]; o.y = acc[i][1]+bb[1];
        o.z = acc[i][2]+bb[2]; o.w = acc[i][3]+bb[3];
        *(float4*)&Yout[(long)(i0 + tg*4 + i)*DM_ + m0 + dg*4] = o;
    }
}

// ---------------------------------------------------------------------------
extern "C" void kernel_launch(void* const* d_in, const int* in_sizes, int n_in,
                              void* d_out, int out_size, void* d_ws, size_t ws_size,
                              hipStream_t stream)
{
    const float* query = (const float*)d_in[0];
    const float* key   = (const float*)d_in[1];
    const float* value = (const float*)d_in[2];
    const float* Wq    = (const float*)d_in[3];
    const float* bq    = (const float*)d_in[4];
    const float* Wk    = (const float*)d_in[5];
    const float* bk    = (const float*)d_in[6];
    const float* Wv    = (const float*)d_in[7];
    const float* bv    = (const float*)d_in[8];
    const float* E_w   = (const float*)d_in[9];
    const float* E_b   = (const float*)d_in[10];
    const float* F_w   = (const float*)d_in[11];
    const float* F_b   = (const float*)d_in[12];
    const float* out_w = (const float*)d_in[13];
    const float* out_b = (const float*)d_in[14];

    float* ws   = (float*)d_ws;
    float* Qb   = ws;                    // [B,H,S,DH]
    float* Kb   = ws + (size_t)NBHSD;    // [B,H,S,DH]
    float* Vb   = ws + (size_t)2*NBHSD;  // [B,H,S,DH]
    float* KEt  = ws + (size_t)3*NBHSD;  // [B,H,T,DH]
    float* VF   = ws + (size_t)4*NBHSD;  // [B,H,T,DH]
    float* MHA  = Qb;                    // reuse Q slot after attn kernel: [B,S,DM]

    float* mha_out = (float*)d_out;                 // [B,S,DM]
    float* attn    = (float*)d_out + OFF_ATTN;      // [B,H,S,T]

    // 1) Q/K/V projections
    qkv_proj_kernel<<<dim3(S_/64, H_, 3*B_), 256, 0, stream>>>(
        query, key, value, Wq, bq, Wk, bk, Wv, bv, Qb, Kb, Vb);

    // 2) KEt[bh][t][d] = sum_s E_w[t,s]*K[bh,s,d] + E_b[t]
    gemm_tile64_kernel<<<dim3(T_/64, B_*H_), 256, 0, stream>>>(
        E_w, 0, S_, Kb, (long)S_*DH_, E_b,
        KEt, (long)H_*T_*DH_, (long)T_*DH_, DH_);
    //    VF[bh][t][d] = sum_s F_w[t,s]*V[bh,s,d] + F_b[t]
    gemm_tile64_kernel<<<dim3(T_/64, B_*H_), 256, 0, stream>>>(
        F_w, 0, S_, Vb, (long)S_*DH_, F_b,
        VF, (long)H_*T_*DH_, (long)T_*DH_, DH_);

    // 3) attn = softmax(Q . KEt^T / 8) -> d_out attn region
    attn_softmax_kernel<<<dim3(S_/16, B_*H_), 256, 0, stream>>>(Qb, KEt, attn);

    // 4) head_out -> MHA[b][s][h*64+d] = sum_t attn[bh,s,t]*VF[bh,t,d]
    gemm_tile64_kernel<<<dim3(S_/64, B_*H_), 256, 0, stream>>>(
        attn, (long)S_*T_, T_, VF, (long)T_*DH_, nullptr,
        MHA, (long)S_*DM_, (long)DH_, DM_);

    // 5) output projection
    outproj_kernel<<<dim3(B_*S_/64, DM_/64), 256, 0, stream>>>(
        MHA, out_w, out_b, mha_out);
}